// Round 1
// baseline (1255.483 us; speedup 1.0000x reference)
//
#include <hip/hip_runtime.h>

// One block per memory row: blockDim.x = D/4 (=256) threads, each moves one float4.
// Row `row` of the output = batch[rel] if rel = (row - mi) mod M < B, else mem[row].
__global__ void copy_update_rows(const float4* __restrict__ mem,
                                 const float4* __restrict__ batch,
                                 float4* __restrict__ out,
                                 const int* __restrict__ d_mi,
                                 int M, int B, int D4) {
    int row = blockIdx.x;
    int col = threadIdx.x;
    int rel = row - *d_mi;
    if (rel < 0) rel += M;
    unsigned g = (unsigned)row * (unsigned)D4 + (unsigned)col;
    if (rel < B) {
        out[g] = batch[(unsigned)rel * (unsigned)D4 + (unsigned)col];
    } else {
        out[g] = mem[g];
    }
}

__global__ void copy_update_conf(const float* __restrict__ mem,
                                 const float* __restrict__ batch,
                                 float* __restrict__ out,
                                 const int* __restrict__ d_mi,
                                 int M, int B) {
    int i = blockIdx.x * blockDim.x + threadIdx.x;
    if (i >= M) return;
    int rel = i - *d_mi;
    if (rel < 0) rel += M;
    out[i] = (rel < B) ? batch[rel] : mem[i];
}

// Single block: mean of B confidences + utilization scalar.
__global__ void mean_and_util(const float* __restrict__ conf,
                              const int* __restrict__ d_mi,
                              const int* __restrict__ d_full,
                              float* __restrict__ out_mean,
                              float* __restrict__ out_util,
                              int B, int M) {
    __shared__ float warp_sums[8];  // up to 512 threads / 64 lanes
    float s = 0.0f;
    for (int i = threadIdx.x; i < B; i += blockDim.x) s += conf[i];
    // wave-64 reduction
    #pragma unroll
    for (int off = 32; off > 0; off >>= 1) s += __shfl_down(s, off);
    int lane = threadIdx.x & 63;
    int wave = threadIdx.x >> 6;
    if (lane == 0) warp_sums[wave] = s;
    __syncthreads();
    if (threadIdx.x == 0) {
        int nwaves = (blockDim.x + 63) >> 6;
        float total = 0.0f;
        for (int w = 0; w < nwaves; ++w) total += warp_sums[w];
        out_mean[0] = total / (float)B;

        int mi = *d_mi;
        int ni = (mi + B) % M;
        bool wrapped = (mi + B) >= M;
        bool full = (*d_full != 0) || wrapped;
        out_util[0] = full ? 1.0f : (float)ni / (float)M;
    }
}

extern "C" void kernel_launch(void* const* d_in, const int* in_sizes, int n_in,
                              void* d_out, int out_size, void* d_ws, size_t ws_size,
                              hipStream_t stream) {
    const float* features     = (const float*)d_in[0];
    const float* predictions  = (const float*)d_in[1];
    const float* confidences  = (const float*)d_in[2];
    const float* mem_feat     = (const float*)d_in[3];
    const float* mem_pred     = (const float*)d_in[4];
    const float* mem_conf     = (const float*)d_in[5];
    const int*   d_mi         = (const int*)d_in[6];
    const int*   d_full       = (const int*)d_in[7];

    const int B  = in_sizes[2];          // 4096
    const int MD = in_sizes[3];          // 102,400,000 (fits in int)
    const int M  = in_sizes[5];          // 100,000
    const int D  = MD / M;               // 1024
    const int D4 = D / 4;                // 256 -> one block per row

    float* out       = (float*)d_out;
    float* out_feat  = out;
    float* out_pred  = out + (size_t)MD;
    float* out_conf  = out + (size_t)2 * MD;
    float* out_mean  = out_conf + M;
    float* out_util  = out_mean + 1;

    copy_update_rows<<<M, D4, 0, stream>>>((const float4*)mem_feat,
                                           (const float4*)features,
                                           (float4*)out_feat, d_mi, M, B, D4);
    copy_update_rows<<<M, D4, 0, stream>>>((const float4*)mem_pred,
                                           (const float4*)predictions,
                                           (float4*)out_pred, d_mi, M, B, D4);
    copy_update_conf<<<(M + 255) / 256, 256, 0, stream>>>(mem_conf, confidences,
                                                          out_conf, d_mi, M, B);
    mean_and_util<<<1, 256, 0, stream>>>(confidences, d_mi, d_full,
                                         out_mean, out_util, B, M);
}